// Round 1
// baseline (410.028 us; speedup 1.0000x reference)
//
#include <hip/hip_runtime.h>

// LatentClassifier collapse (all f32 I/O):
//   All depth-loop layernorms act on singleton axes -> LN(x) == bias exactly.
//   => h = x + c[t],  c[t] = sum_i alpha_i*w2_i*(beta_i*R_i[t] + sgu_proj_b[i,t]) + b2_i
//   out = (gelu((x+c) @ P^T + pooler_b)) @ cls_w^T + cls_b
//   c per-column => (x+c)@P^T = x@P^T + d[s], d[s] = sum_t c[t]*P[s,t]
// FP32 inputs, no fp32 MFMA -> convert x,P to bf16 once (ws), one 4096^3 bf16
// MFMA GEMM with fused gelu/cls epilogue atomicAdd into d_out.
//
// R3: XOR swizzle -> 0 bank conflicts, 1025 TF. R4: 256x128 tile -> 1018 TF,
// MfmaUtil 44%: limiter is the per-K-step vmcnt(0) drain forced by
// __syncthreads (stage -> full drain -> compute serialization).
// R5: 256x256 tile, 512 thr (8 waves), 128KB double-buffered LDS, counted
// vmcnt(8) + raw s_barrier -> next tile's loads stay in flight across the
// whole MFMA cluster (T3+T4). setprio around MFMAs (T5), bijective XCD
// swizzle (T1). Also: e folded into cvt (kills 32MB e_kernel pass), rowsum
// folded into c_kernel (beta==0 fast path). 5 launches -> 3.

#define K_DIM 4096

typedef __bf16 bf16x8 __attribute__((ext_vector_type(8)));
typedef float f32x4 __attribute__((ext_vector_type(4)));

__device__ __forceinline__ ushort f2bf(float f) {
    unsigned int u = __float_as_uint(f);
    u = (u + 0x7fffu + ((u >> 16) & 1u)) >> 16;  // RTNE
    return (ushort)u;
}

__device__ __forceinline__ float gelu_exact(float x) {
    return 0.5f * x * (1.0f + erff(x * 0.70710678118654752440f));
}

__device__ __forceinline__ void gld16(const void* g, void* l) {
    __builtin_amdgcn_global_load_lds(
        (__attribute__((address_space(1))) void*)(g),
        (__attribute__((address_space(3))) void*)(l), 16, 0, 0);
}

// ---------- K1: c[t] (+R rowsum inline, beta==0 fast path); init e, out -------
__global__ __launch_bounds__(256) void c_kernel(const float* __restrict__ ln1_b,
                                                const float* __restrict__ cp1_w,
                                                const float* __restrict__ cp1_b,
                                                const float* __restrict__ sgu_ln_b,
                                                const float* __restrict__ sgu_proj_w,
                                                const float* __restrict__ sgu_proj_b,
                                                const float* __restrict__ cp2_w,
                                                const float* __restrict__ cp2_b,
                                                const float* __restrict__ cls_b,
                                                const float* __restrict__ pooler_b,
                                                float* __restrict__ c,
                                                float* __restrict__ e,
                                                float* __restrict__ out) {
    int t = blockIdx.x * 256 + threadIdx.x;  // 0..4095
    float cv = 0.0f;
#pragma unroll
    for (int i = 0; i < 2; ++i) {
        float alpha = gelu_exact(ln1_b[i] * cp1_w[i * 2 + 0] + cp1_b[i * 2 + 0]);
        float beta  = sgu_ln_b[i];
        float Ri = 0.0f;
        if (beta != 0.0f) {  // never taken with these inputs; kept for correctness
            const float* pr = sgu_proj_w + ((size_t)i * 4096 + t) * K_DIM;
            for (int k = 0; k < K_DIM; k += 4) {
                float4 pv = *(const float4*)&pr[k];
                Ri += pv.x + pv.y + pv.z + pv.w;
            }
        }
        float v = beta * Ri + sgu_proj_b[i * 4096 + t];
        cv += alpha * v * cp2_w[i] + cp2_b[i];
    }
    c[t]   = cv;
    e[t]   = pooler_b[t];  // e accumulated by cvt2_kernel atomics
    out[t] = cls_b[0];     // d_out poisoned before every call -> re-init here
}

// ---------- K2: f32->bf16 convert of x and pooler_w; P-half also accumulates
//               e[row] += sum_col P[row,col]*c[col] (wave-reduced atomic) ------
__global__ __launch_bounds__(256) void cvt2_kernel(const float* __restrict__ s0,
                                                   ushort* __restrict__ d0,
                                                   const float* __restrict__ s1,
                                                   ushort* __restrict__ d1,
                                                   const float* __restrict__ c,
                                                   float* __restrict__ e) {
    int b = blockIdx.x;
    bool isP = (b >= 8192);
    const float* src = isP ? s1 : s0;
    ushort* dst = isP ? d1 : d0;
    int i = (b & 8191) * 256 + threadIdx.x;  // 8 floats each
    const float4* s4 = (const float4*)src + (size_t)i * 2;
    float4 a = s4[0], q = s4[1];
    union { ushort u[8]; uint4 v; } r;
    r.u[0] = f2bf(a.x); r.u[1] = f2bf(a.y); r.u[2] = f2bf(a.z); r.u[3] = f2bf(a.w);
    r.u[4] = f2bf(q.x); r.u[5] = f2bf(q.y); r.u[6] = f2bf(q.z); r.u[7] = f2bf(q.w);
    ((uint4*)dst)[i] = r.v;
    if (isP) {
        // wave's 64 units are 512 consecutive floats inside row i>>9
        int col = (i << 3) & 4095;
        float s = a.x * c[col + 0] + a.y * c[col + 1] + a.z * c[col + 2] + a.w * c[col + 3]
                + q.x * c[col + 4] + q.y * c[col + 5] + q.z * c[col + 6] + q.w * c[col + 7];
#pragma unroll
        for (int m = 1; m < 64; m <<= 1) s += __shfl_xor(s, m);
        if ((threadIdx.x & 63) == 0) atomicAdd(&e[i >> 9], s);
    }
}

// ---------- K3: Y = x @ P^T (bf16 MFMA); fused gelu(Y+e)*cls_w row-reduce -------
// 256x256 block tile, BK=64, 8 waves (2Mx4N), wave tile 128x64 (8x4 frags of
// 16x16x32). LDS 128KB: As[2]/Bs[2] double buffer. byte(row,chunk) =
// row*128 + (chunk^(row&7))*16; swizzle applied to the GLOBAL chunk on staging
// (global_load_lds dst = t*16, linear). Reads: chunk = (kk*4+g)^(lo&7) -> all
// phases 2-way on banks (free).
// Pipeline: STAGE(next tile, 8 gld16/thread) -> s_waitcnt vmcnt(8) (prev tile
// retired, next tile's 8 still flying) -> s_barrier -> ds_read+MFMA -> s_barrier.
// Never drains vmcnt to 0 in the main loop (T4); raw s_barrier avoids the
// compiler's vmcnt(0) drain that __syncthreads would force.
__global__ __launch_bounds__(512, 2) void gemm_kernel(const ushort* __restrict__ X,
                                                      const ushort* __restrict__ P,
                                                      const float* __restrict__ clsW,
                                                      const float* __restrict__ e,
                                                      float* __restrict__ accOut) {
    __shared__ __align__(16) ushort As[2][256 * 64];  // 2 x 32 KB
    __shared__ __align__(16) ushort Bs[2][256 * 64];  // 2 x 32 KB

    const int t = threadIdx.x;
    // bijective XCD swizzle (256 blocks % 8 XCDs == 0): XCD x gets 32
    // contiguous swz ids = 2 full bRow stripes -> A panels L2-resident.
    const int flat = blockIdx.x;
    const int swz = (flat & 7) * 32 + (flat >> 3);
    const int bRow = swz >> 4, bCol = swz & 15;

    const int lane = t & 63, wv = t >> 6;
    const int g = lane >> 4, lo = lane & 15;
    const int wm = wv >> 2, wn = wv & 3;  // 2 x 4 waves

    f32x4 zero4 = {0.f, 0.f, 0.f, 0.f};
    f32x4 acc[8][4];
#pragma unroll
    for (int mi = 0; mi < 8; ++mi)
#pragma unroll
        for (int ni = 0; ni < 4; ++ni) acc[mi][ni] = zero4;

    // staging: thread t covers rows (t>>3)+64*r, slot t&7 holds global chunk
    // (t&7)^(row&7) (row&7 == (t>>3)&7 since 64r = 0 mod 8); dst byte = t*16 + r*8192.
    const int sr = t >> 3;                      // 0..63
    const int cs = (t & 7) ^ (sr & 7);          // swizzled global 16B-chunk
    const ushort* gA = X + (size_t)(bRow * 256 + sr) * K_DIM + cs * 8;
    const ushort* gB = P + (size_t)(bCol * 256 + sr) * K_DIM + cs * 8;
    char* lA0 = (char*)&As[0][0] + t * 16;
    char* lB0 = (char*)&Bs[0][0] + t * 16;

#define STAGE(buf, k0)                                                            \
    do {                                                                          \
        _Pragma("unroll") for (int r_ = 0; r_ < 4; ++r_)                          \
            gld16(gA + (size_t)(r_ * 64) * K_DIM + (k0), lA0 + (buf)*32768 + r_ * 8192); \
        _Pragma("unroll") for (int r_ = 0; r_ < 4; ++r_)                          \
            gld16(gB + (size_t)(r_ * 64) * K_DIM + (k0), lB0 + (buf)*32768 + r_ * 8192); \
    } while (0)

#define COMPUTE(buf)                                                              \
    do {                                                                          \
        _Pragma("unroll") for (int kk = 0; kk < 2; ++kk) {                        \
            const int ch = (((kk << 2) | g) ^ (lo & 7)) << 3;                     \
            bf16x8 af[8], bfr[4];                                                 \
            _Pragma("unroll") for (int mi = 0; mi < 8; ++mi)                      \
                af[mi] = *(const bf16x8*)&As[buf][(wm * 128 + mi * 16 + lo) * 64 + ch]; \
            _Pragma("unroll") for (int ni = 0; ni < 4; ++ni)                      \
                bfr[ni] = *(const bf16x8*)&Bs[buf][(wn * 64 + ni * 16 + lo) * 64 + ch]; \
            __builtin_amdgcn_s_setprio(1);                                        \
            _Pragma("unroll") for (int mi = 0; mi < 8; ++mi)                      \
                _Pragma("unroll") for (int ni = 0; ni < 4; ++ni)                  \
                    acc[mi][ni] = __builtin_amdgcn_mfma_f32_16x16x32_bf16(        \
                        af[mi], bfr[ni], acc[mi][ni], 0, 0, 0);                   \
            __builtin_amdgcn_s_setprio(0);                                        \
        }                                                                         \
    } while (0)

    STAGE(0, 0);  // tile 0 -> buf0 (8 loads in flight)
#pragma unroll 1
    for (int k0 = 64; k0 < 3968; k0 += 128) {
        // stages tiles k0/64 (odd->buf1) and k0/64+1 (even->buf0);
        // computes tiles k0/64-1 (buf0) and k0/64 (buf1).
        STAGE(1, k0);
        asm volatile("s_waitcnt vmcnt(8)\n\ts_barrier" ::: "memory");
        COMPUTE(0);
        asm volatile("s_barrier" ::: "memory");
        STAGE(0, k0 + 64);
        asm volatile("s_waitcnt vmcnt(8)\n\ts_barrier" ::: "memory");
        COMPUTE(1);
        asm volatile("s_barrier" ::: "memory");
    }
    // tail: tiles 62 (staged, buf0) and 63
    STAGE(1, 4032);
    asm volatile("s_waitcnt vmcnt(8)\n\ts_barrier" ::: "memory");
    COMPUTE(0);  // tile 62
    asm volatile("s_barrier" ::: "memory");
    asm volatile("s_waitcnt vmcnt(0)\n\ts_barrier" ::: "memory");
    COMPUTE(1);  // tile 63

#undef STAGE
#undef COMPUTE

    // Epilogue: C/D layout col=lane&15, row=(lane>>4)*4+reg (m89-verified).
    int sColBase = bCol * 256 + wn * 64 + lo;
    float eb[4], cw[4];
#pragma unroll
    for (int ni = 0; ni < 4; ++ni) {
        int s = sColBase + ni * 16;
        eb[ni] = e[s];
        cw[ni] = clsW[s];
    }
#pragma unroll
    for (int mi = 0; mi < 8; ++mi) {
        int rowBase = bRow * 256 + wm * 128 + mi * 16 + g * 4;
#pragma unroll
        for (int r = 0; r < 4; ++r) {
            float sum = 0.0f;
#pragma unroll
            for (int ni = 0; ni < 4; ++ni) {
                float y = acc[mi][ni][r] + eb[ni];
                sum += gelu_exact(y) * cw[ni];
            }
            sum += __shfl_xor(sum, 1);
            sum += __shfl_xor(sum, 2);
            sum += __shfl_xor(sum, 4);
            sum += __shfl_xor(sum, 8);
            if (lo == 0) atomicAdd(&accOut[rowBase + r], sum);
        }
    }
}

extern "C" void kernel_launch(void* const* d_in, const int* in_sizes, int n_in,
                              void* d_out, int out_size, void* d_ws, size_t ws_size,
                              hipStream_t stream) {
    const float* x          = (const float*)d_in[0];
    const float* ln1_b      = (const float*)d_in[2];
    const float* cp1_w      = (const float*)d_in[3];
    const float* cp1_b      = (const float*)d_in[4];
    const float* sgu_ln_b   = (const float*)d_in[6];
    const float* sgu_proj_w = (const float*)d_in[7];
    const float* sgu_proj_b = (const float*)d_in[8];
    const float* cp2_w      = (const float*)d_in[9];
    const float* cp2_b      = (const float*)d_in[10];
    const float* pooler_w   = (const float*)d_in[11];
    const float* pooler_b   = (const float*)d_in[12];
    const float* cls_w      = (const float*)d_in[13];
    const float* cls_b      = (const float*)d_in[14];

    // ws layout: xb (32MB bf16) | pb (32MB bf16) | c(16KB) | e(16KB)
    ushort* xb = (ushort*)d_ws;                  // 4096*4096 bf16
    ushort* pb = xb + (size_t)K_DIM * K_DIM;     // 4096*4096 bf16
    float*  fs = (float*)(pb + (size_t)K_DIM * K_DIM);
    float* c_buf = fs;
    float* e_buf = fs + 4096;
    float* out   = (float*)d_out;

    c_kernel<<<16, 256, 0, stream>>>(ln1_b, cp1_w, cp1_b, sgu_ln_b, sgu_proj_w,
                                     sgu_proj_b, cp2_w, cp2_b, cls_b, pooler_b,
                                     c_buf, e_buf, out);
    cvt2_kernel<<<16384, 256, 0, stream>>>(x, xb, pooler_w, pb, c_buf, e_buf);
    gemm_kernel<<<256, 512, 0, stream>>>(xb, pb, cls_w, e_buf, out);
}